// Round 6
// baseline (113.639 us; speedup 1.0000x reference)
//
#include <hip/hip_runtime.h>

// Non-backtracking random walk, 32 steps.
// out = [walks (steps+1,n) ; walk_edges (steps,n)] int32.
//
// R14: chain de-lockstep. R11-R13 showed the walker is insensitive to
// gather structure (2->1 req/step: -2us; 1->4 loads: +0.5us) — not
// request-throughput bound, not dependent-load bound; only L2 residency
// matters (R11: +7.5us when table blew L2). Remaining theories:
// (a) latency-exposure: 782 waves on 1024 SIMDs (<1 wave/SIMD) with
//     CHAINS=2 chains advancing in LOCKSTEP (one vmcnt drain covers both
//     loads) -> full gather latency exposed every step;
// (b) harness floor: window dominated by the unconditional 44us ws fill
//     + harness memsets/restores, walker already small.
// Test: CHAINS=1 — two independent waves instead of two lockstep chains
// per thread. 1563 waves (~1.5/SIMD) gives true wave-level latency
// interleaving. Walker = R12's best-measured body (single dwordx2 +
// alignbit decode + predicated alt, same 36B/row 3.6MB L2-resident
// table); choices = per-step NT load with 1-step prefetch. Pack kernel =
// R13's verified version, verbatim. (a) right -> ~96-100us; (b) right ->
// unchanged -> declare controllable roofline.

#define DEG 16
#define NMAX 131072          // row-count limit of the packed table
#define PACK_BLOCK 256
#define ENT_MASK 0x3FFFFu    // 18-bit entries

// Packed adjacency: 9 dwords/row = 16 x 18-bit entries, +2 dwords pad so
// the last row's entry-15 dwordx2 (dwords 8,9) stays in-bounds.
__device__ unsigned int g_pk32[(size_t)NMAX * 9 + 2];
__device__ int g_flag;   // == epoch  =>  take the general fallback

__global__ __launch_bounds__(PACK_BLOCK) void pack_check_kernel(
    const int* __restrict__ adj_nodes,
    const int* __restrict__ adj_offset,
    const int* __restrict__ degrees,
    int n, int epoch) {
    __shared__ __align__(16) unsigned int lds[PACK_BLOCK * 9];

    int tid = threadIdx.x;
    int blockStart = blockIdx.x * PACK_BLOCK;
    int v = blockStart + tid;

    bool bad = false;
    if (v < n) {
        bad = (degrees[v] != DEG) || (adj_offset[v] != v * DEG);

        const uint4* row4 = (const uint4*)(adj_nodes + (size_t)v * DEG); // 64B-aligned
        uint4 r[4];
        r[0] = row4[0]; r[1] = row4[1]; r[2] = row4[2]; r[3] = row4[3];
        const unsigned* rr = (const unsigned*)r;

        unsigned dw[9];
#pragma unroll
        for (int j = 0; j < 9; ++j) dw[j] = 0u;
#pragma unroll
        for (int e = 0; e < 16; ++e) {
            unsigned id = rr[e];
            if (id >= 262144u) bad = true;            // needs >18 bits
            unsigned s   = 18u * (unsigned)e;
            unsigned d   = s >> 5;
            unsigned off = s & 31u;
            dw[d] |= id << off;
            if (off > 14u) dw[d + 1] |= id >> (32u - off);  // field crosses dword
        }
        // register-level decode check through the walker's exact alignbit
        // path (guards pack logic; ~100 VALU ops, no memory)
#pragma unroll
        for (int e = 0; e < 16; ++e) {
            unsigned s   = 18u * (unsigned)e;
            unsigned d   = s >> 5;
            unsigned off = s & 31u;
            unsigned hi  = (off > 14u) ? dw[d + 1] : 0u;   // crossing d's are <=7
            unsigned id  = __builtin_amdgcn_alignbit(hi, dw[d], off) & ENT_MASK;
            if (id != rr[e]) bad = true;
        }
#pragma unroll
        for (int j = 0; j < 9; ++j) lds[tid * 9 + j] = dw[j];
    }
    __syncthreads();

    // coalesced flush: 256 rows * 9 dwords = 2304 dwords = 576 uint4
    int rows = n - blockStart;
    if (rows > PACK_BLOCK) rows = PACK_BLOCK;
    unsigned int* dstBase = g_pk32 + (size_t)blockStart * 9;   // 16B-aligned (9216B/block)
    if (rows == PACK_BLOCK) {
        uint4* dst4 = (uint4*)dstBase;
        const uint4* src4 = (const uint4*)lds;
        for (int i = tid; i < (PACK_BLOCK * 9) / 4; i += PACK_BLOCK)
            dst4[i] = src4[i];
    } else {
        int ndw = rows * 9;
        for (int i = tid; i < ndw; i += PACK_BLOCK) dstBase[i] = lds[i];
    }

    if (bad) g_flag = epoch;
}

template <int STEPS>
__global__ __launch_bounds__(256) void walker_fast6(
    const int* __restrict__ choices,
    int* __restrict__ out, int n, int epoch,
    const int* __restrict__ adj_nodes,
    const int* __restrict__ adj_offset,
    const int* __restrict__ degrees) {

    int w = blockIdx.x * blockDim.x + threadIdx.x;
    if (w >= n) return;

    int* walks      = out;                    // [STEPS+1, n]
    int* walk_edges = out + (STEPS + 1) * n;  // [STEPS, n]

    __builtin_nontemporal_store(w, &walks[w]);

    if (g_flag != epoch) {
        // ---- fast path: 1 chain/thread, single dwordx2 gather + predicated alt ----
        int prev = -1, cur = w;
        int ch_next = __builtin_nontemporal_load(&choices[w]);
#pragma unroll
        for (int i = 0; i < STEPS; ++i) {
            unsigned ch = (unsigned)ch_next;
            if (i + 1 < STEPS)   // prefetch next step's choice; overlaps the gather
                ch_next = __builtin_nontemporal_load(&choices[(i + 1) * n + w]);

            unsigned e = ch & (DEG - 1);
            const unsigned* row = g_pk32 + (size_t)(unsigned)cur * 9u;
            unsigned s = 18u * e, d = s >> 5, f = s & 31u;

            uint2 q = *(const uint2*)(row + d);       // one 8B gather (4B-aligned)
            int cand = (int)(__builtin_amdgcn_alignbit(q.y, q.x, f) & ENT_MASK);

            int nw = cand;
            unsigned ef = e;
            // predicated alt: ~4 lanes/wave, same row (L1/L2-hot line)
            if (cand == prev) {
                unsigned a  = (e + 1u + ch % (DEG - 1)) & (DEG - 1);
                unsigned sa = 18u * a, da = sa >> 5, fa = sa & 31u;
                uint2 qa = *(const uint2*)(row + da);
                nw = (int)(__builtin_amdgcn_alignbit(qa.y, qa.x, fa) & ENT_MASK);
                ef = a;
            }

            __builtin_nontemporal_store(nw, &walks[(i + 1) * n + w]);
            __builtin_nontemporal_store((cur << 4) + (int)ef, &walk_edges[i * n + w]);
            prev = cur; cur = nw;
        }
    } else {
        // ---- general fallback: 2 dependent gathers/step from raw CSR ----
        int prev = -1, cur = w;
        for (int i = 0; i < STEPS; ++i) {
            int chv = choices[i * n + w];
            int deg = degrees[cur];
            int off = adj_offset[cur];
            int nb  = deg - 1 > 1 ? deg - 1 : 1;

            int e      = chv % deg;
            int chosen = off + e;
            int alt    = off + (e + 1 + chv % nb) % deg;

            int nv0 = adj_nodes[chosen];
            int nv1 = adj_nodes[alt];

            bool bt = (nv0 == prev);
            int nw  = bt ? nv1 : nv0;
            walks[(i + 1) * n + w] = nw;
            walk_edges[i * n + w]  = bt ? alt : chosen;
            prev = cur;
            cur  = nw;
        }
    }
}

__global__ __launch_bounds__(256) void walker_generic(
    const int* __restrict__ adj_nodes,
    const int* __restrict__ adj_offset,
    const int* __restrict__ degrees,
    const int* __restrict__ choices,
    int* __restrict__ out, int n, int steps) {

    int w = blockIdx.x * blockDim.x + threadIdx.x;
    if (w >= n) return;

    int* walks      = out;
    int* walk_edges = out + (steps + 1) * n;
    walks[w] = w;

    int prev = -1, cur = w;
    for (int i = 0; i < steps; ++i) {
        int chv = choices[i * n + w];
        int deg = degrees[cur];
        int off = adj_offset[cur];
        int nb  = deg - 1 > 1 ? deg - 1 : 1;

        int e      = chv % deg;
        int chosen = off + e;
        int alt    = off + (e + 1 + chv % nb) % deg;

        int nv0 = adj_nodes[chosen];
        int nv1 = adj_nodes[alt];

        bool bt = (nv0 == prev);
        int nw  = bt ? nv1 : nv0;
        walks[(i + 1) * n + w] = nw;
        walk_edges[i * n + w]  = bt ? alt : chosen;
        prev = cur;
        cur  = nw;
    }
}

extern "C" void kernel_launch(void* const* d_in, const int* in_sizes, int n_in,
                              void* d_out, int out_size, void* d_ws, size_t ws_size,
                              hipStream_t stream) {
    // inputs: 0=x (unused), 1=adj_nodes, 2=adj_offset, 3=degrees, 4=choices
    const int* adj_nodes  = (const int*)d_in[1];
    const int* adj_offset = (const int*)d_in[2];
    const int* degrees    = (const int*)d_in[3];
    const int* choices    = (const int*)d_in[4];
    int* out = (int*)d_out;

    int n     = in_sizes[2];
    int steps = in_sizes[4] / n;

    if (steps == 32 && n <= NMAX) {
        static int s_epoch = 0;
        int epoch = ++s_epoch;   // baked into a captured graph; pack reruns
                                 // per replay, badness is input-constant

        int pg = (n + PACK_BLOCK - 1) / PACK_BLOCK;
        pack_check_kernel<<<pg, PACK_BLOCK, 0, stream>>>(adj_nodes, adj_offset,
                                                         degrees, n, epoch);

        int wb = 256, wg = (n + wb - 1) / wb;
        walker_fast6<32><<<wg, wb, 0, stream>>>(choices, out, n, epoch,
                                                adj_nodes, adj_offset, degrees);
    } else {
        int block = 256, grid = (n + block - 1) / block;
        walker_generic<<<grid, block, 0, stream>>>(adj_nodes, adj_offset,
                                                   degrees, choices, out, n, steps);
    }
}

// Round 7
// 102.357 us; speedup vs baseline: 1.1102x; 1.1102x over previous
//
#include <hip/hip_runtime.h>

// Non-backtracking random walk, 32 steps.
// out = [walks (steps+1,n) ; walk_edges (steps,n)] int32.
//
// R15: recombination of best-measured pieces. Ledger: R12 (104.9, best) =
// CHAINS=2 + choices burst + single dwordx2/alignbit + predicated alt +
// validate kernel (+3us). R13 (105.4) = dual gathers (+3.5us walker) but
// no validate. R14 (113.6) = per-step choices load: vmcnt drains the cold
// choices stream (~900cyc HBM) on EVERY step's critical path -> burst
// preload is essential. R15 = R12's walker VERBATIM + R13's pack (decode
// check folded in registers, validate deleted) + epoch sentinel (no
// memset dispatch). Expect ~102us; remaining window = ~44us unconditional
// ws-poison fill + harness dispatches + ~10us of near-floor kernels.

#define DEG 16
#define CHAINS 2
#define NMAX 131072          // row-count limit of the packed table
#define PACK_BLOCK 256
#define ENT_MASK 0x3FFFFu    // 18-bit entries

// Packed adjacency: 9 dwords/row = 16 x 18-bit entries, +2 dwords pad so
// the last row's entry-15 dwordx2 (dwords 8,9) stays in-bounds.
__device__ unsigned int g_pk32[(size_t)NMAX * 9 + 2];
__device__ int g_flag;   // == epoch  =>  take the general fallback

__global__ __launch_bounds__(PACK_BLOCK) void pack_check_kernel(
    const int* __restrict__ adj_nodes,
    const int* __restrict__ adj_offset,
    const int* __restrict__ degrees,
    int n, int epoch) {
    __shared__ __align__(16) unsigned int lds[PACK_BLOCK * 9];

    int tid = threadIdx.x;
    int blockStart = blockIdx.x * PACK_BLOCK;
    int v = blockStart + tid;

    bool bad = false;
    if (v < n) {
        bad = (degrees[v] != DEG) || (adj_offset[v] != v * DEG);

        const uint4* row4 = (const uint4*)(adj_nodes + (size_t)v * DEG); // 64B-aligned
        uint4 r[4];
        r[0] = row4[0]; r[1] = row4[1]; r[2] = row4[2]; r[3] = row4[3];
        const unsigned* rr = (const unsigned*)r;

        unsigned dw[9];
#pragma unroll
        for (int j = 0; j < 9; ++j) dw[j] = 0u;
#pragma unroll
        for (int e = 0; e < 16; ++e) {
            unsigned id = rr[e];
            if (id >= 262144u) bad = true;            // needs >18 bits
            unsigned s   = 18u * (unsigned)e;
            unsigned d   = s >> 5;
            unsigned off = s & 31u;
            dw[d] |= id << off;
            if (off > 14u) dw[d + 1] |= id >> (32u - off);  // field crosses dword
        }
        // register-level decode check through the walker's exact alignbit
        // path (guards pack logic; ~100 VALU ops, no memory traffic)
#pragma unroll
        for (int e = 0; e < 16; ++e) {
            unsigned s   = 18u * (unsigned)e;
            unsigned d   = s >> 5;
            unsigned off = s & 31u;
            unsigned hi  = (off > 14u) ? dw[d + 1] : 0u;   // crossing d's are <=7
            unsigned id  = __builtin_amdgcn_alignbit(hi, dw[d], off) & ENT_MASK;
            if (id != rr[e]) bad = true;
        }
#pragma unroll
        for (int j = 0; j < 9; ++j) lds[tid * 9 + j] = dw[j];
    }
    __syncthreads();

    // coalesced flush: 256 rows * 9 dwords = 2304 dwords = 576 uint4
    int rows = n - blockStart;
    if (rows > PACK_BLOCK) rows = PACK_BLOCK;
    unsigned int* dstBase = g_pk32 + (size_t)blockStart * 9;   // 16B-aligned (9216B/block)
    if (rows == PACK_BLOCK) {
        uint4* dst4 = (uint4*)dstBase;
        const uint4* src4 = (const uint4*)lds;
        for (int i = tid; i < (PACK_BLOCK * 9) / 4; i += PACK_BLOCK)
            dst4[i] = src4[i];
    } else {
        int ndw = rows * 9;
        for (int i = tid; i < ndw; i += PACK_BLOCK) dstBase[i] = lds[i];
    }

    if (bad) g_flag = epoch;
}

template <int STEPS>
__global__ __launch_bounds__(64) void walker_fast7(
    const int* __restrict__ choices,
    int* __restrict__ out, int n, int h, int epoch,
    const int* __restrict__ adj_nodes,
    const int* __restrict__ adj_offset,
    const int* __restrict__ degrees) {

    int t = blockIdx.x * blockDim.x + threadIdx.x;
    if (t >= h) return;

    int* walks      = out;                    // [STEPS+1, n]
    int* walk_edges = out + (STEPS + 1) * n;  // [STEPS, n]

    int w0 = t;
    int w1 = t + h;
    bool has1 = (w1 < n);
    int w1s = has1 ? w1 : w0;

    __builtin_nontemporal_store(w0, &walks[w0]);
    if (has1) __builtin_nontemporal_store(w1, &walks[w1]);

    if (g_flag != epoch) {
        // ---- fast path: uniform CSR deg=16, one dwordx2 gather per step ----
        // 32-deep choices burst: pays the cold-stream vmcnt drain ONCE
        // (R14 showed per-step loads put ~900cyc HBM latency on every step)
        int c0[STEPS], c1[STEPS];
#pragma unroll
        for (int i = 0; i < STEPS; ++i) {
            c0[i] = __builtin_nontemporal_load(&choices[i * n + w0]);
            c1[i] = __builtin_nontemporal_load(&choices[i * n + w1s]);
        }

        int prev0 = -1, cur0 = w0;
        int prev1 = -1, cur1 = w1s;
#pragma unroll
        for (int i = 0; i < STEPS; ++i) {
            unsigned ch0 = (unsigned)c0[i];
            unsigned ch1 = (unsigned)c1[i];
            unsigned e0 = ch0 & (DEG - 1);
            unsigned e1 = ch1 & (DEG - 1);

            const unsigned* row0 = g_pk32 + (size_t)(unsigned)cur0 * 9u;
            const unsigned* row1 = g_pk32 + (size_t)(unsigned)cur1 * 9u;

            unsigned s0 = 18u * e0, d0 = s0 >> 5, f0 = s0 & 31u;
            unsigned s1 = 18u * e1, d1 = s1 >> 5, f1 = s1 & 31u;

            // two unconditional gathers (1 per chain), issued together
            uint2 q0 = *(const uint2*)(row0 + d0);
            uint2 q1 = *(const uint2*)(row1 + d1);

            int n00 = (int)(__builtin_amdgcn_alignbit(q0.y, q0.x, f0) & ENT_MASK);
            int n10 = (int)(__builtin_amdgcn_alignbit(q1.y, q1.x, f1) & ENT_MASK);

            int nw0 = n00, nw1 = n10;
            unsigned ef0 = e0, ef1 = e1;
            // predicated alt gathers: same row, ~2-4 lanes/wave
            if (n00 == prev0) {
                unsigned a0 = (e0 + 1u + ch0 % (DEG - 1)) & (DEG - 1);
                unsigned sa = 18u * a0, da = sa >> 5, fa = sa & 31u;
                uint2 qa = *(const uint2*)(row0 + da);
                nw0 = (int)(__builtin_amdgcn_alignbit(qa.y, qa.x, fa) & ENT_MASK);
                ef0 = a0;
            }
            if (n10 == prev1) {
                unsigned a1 = (e1 + 1u + ch1 % (DEG - 1)) & (DEG - 1);
                unsigned sb = 18u * a1, db = sb >> 5, fb = sb & 31u;
                uint2 qb = *(const uint2*)(row1 + db);
                nw1 = (int)(__builtin_amdgcn_alignbit(qb.y, qb.x, fb) & ENT_MASK);
                ef1 = a1;
            }

            int ce0 = (cur0 << 4) + (int)ef0;
            int ce1 = (cur1 << 4) + (int)ef1;

            __builtin_nontemporal_store(nw0, &walks[(i + 1) * n + w0]);
            __builtin_nontemporal_store(ce0, &walk_edges[i * n + w0]);
            if (has1) {
                __builtin_nontemporal_store(nw1, &walks[(i + 1) * n + w1]);
                __builtin_nontemporal_store(ce1, &walk_edges[i * n + w1]);
            }
            prev0 = cur0; cur0 = nw0;
            prev1 = cur1; cur1 = nw1;
        }
    } else {
        // ---- general fallback: 2 dependent gathers/step ----
        for (int k = 0; k < 2; ++k) {
            int w = (k == 0) ? w0 : w1;
            if (w >= n) break;
            int prev = -1, cur = w;
            for (int i = 0; i < STEPS; ++i) {
                int chv = choices[i * n + w];
                int deg = degrees[cur];
                int off = adj_offset[cur];
                int nb  = deg - 1 > 1 ? deg - 1 : 1;

                int e      = chv % deg;
                int chosen = off + e;
                int alt    = off + (e + 1 + chv % nb) % deg;

                int nv0 = adj_nodes[chosen];
                int nv1 = adj_nodes[alt];

                bool bt = (nv0 == prev);
                int nw  = bt ? nv1 : nv0;
                walks[(i + 1) * n + w] = nw;
                walk_edges[i * n + w]  = bt ? alt : chosen;
                prev = cur;
                cur  = nw;
            }
        }
    }
}

__global__ __launch_bounds__(256) void walker_generic(
    const int* __restrict__ adj_nodes,
    const int* __restrict__ adj_offset,
    const int* __restrict__ degrees,
    const int* __restrict__ choices,
    int* __restrict__ out, int n, int steps) {

    int w = blockIdx.x * blockDim.x + threadIdx.x;
    if (w >= n) return;

    int* walks      = out;
    int* walk_edges = out + (steps + 1) * n;
    walks[w] = w;

    int prev = -1, cur = w;
    for (int i = 0; i < steps; ++i) {
        int chv = choices[i * n + w];
        int deg = degrees[cur];
        int off = adj_offset[cur];
        int nb  = deg - 1 > 1 ? deg - 1 : 1;

        int e      = chv % deg;
        int chosen = off + e;
        int alt    = off + (e + 1 + chv % nb) % deg;

        int nv0 = adj_nodes[chosen];
        int nv1 = adj_nodes[alt];

        bool bt = (nv0 == prev);
        int nw  = bt ? nv1 : nv0;
        walks[(i + 1) * n + w] = nw;
        walk_edges[i * n + w]  = bt ? alt : chosen;
        prev = cur;
        cur  = nw;
    }
}

extern "C" void kernel_launch(void* const* d_in, const int* in_sizes, int n_in,
                              void* d_out, int out_size, void* d_ws, size_t ws_size,
                              hipStream_t stream) {
    // inputs: 0=x (unused), 1=adj_nodes, 2=adj_offset, 3=degrees, 4=choices
    const int* adj_nodes  = (const int*)d_in[1];
    const int* adj_offset = (const int*)d_in[2];
    const int* degrees    = (const int*)d_in[3];
    const int* choices    = (const int*)d_in[4];
    int* out = (int*)d_out;

    int n     = in_sizes[2];
    int steps = in_sizes[4] / n;

    if (steps == 32 && n <= NMAX) {
        static int s_epoch = 0;
        int epoch = ++s_epoch;   // baked into a captured graph; pack reruns
                                 // per replay, badness is input-constant

        int pg = (n + PACK_BLOCK - 1) / PACK_BLOCK;
        pack_check_kernel<<<pg, PACK_BLOCK, 0, stream>>>(adj_nodes, adj_offset,
                                                         degrees, n, epoch);

        int h  = (n + CHAINS - 1) / CHAINS;
        int wb = 64, wg = (h + wb - 1) / wb;
        walker_fast7<32><<<wg, wb, 0, stream>>>(choices, out, n, h, epoch,
                                                adj_nodes, adj_offset, degrees);
    } else {
        int block = 256, grid = (n + block - 1) / block;
        walker_generic<<<grid, block, 0, stream>>>(adj_nodes, adj_offset,
                                                   degrees, choices, out, n, steps);
    }
}

// Round 8
// 101.975 us; speedup vs baseline: 1.1144x; 1.0037x over previous
//
#include <hip/hip_runtime.h>

// Non-backtracking random walk, 32 steps.
// out = [walks (steps+1,n) ; walk_edges (steps,n)] int32.
//
// R16: clean de-lockstep test. R15 (102.4, best) = R12 walker (CHAINS=2,
// 32-deep choices burst, single dwordx2+alignbit, predicated alt) + pack
// with in-register decode check + epoch sentinel. R14's CHAINS=1 test was
// CONFOUNDED: it also switched the choices burst to per-step loads, and
// that (vmcnt draining a cold HBM stream every step) explains its
// regression. Untested quadrant: CHAINS=1 WITH the full burst. Rationale:
// 782 waves on 1024 SIMDs (<1/SIMD) leaves every gather's latency fully
// exposed (lockstep chains share one vmcnt drain; no wave to switch to).
// CHAINS=1 doubles waves to 1563 (~1.5/SIMD) for true wave-level latency
// interleaving, halves per-thread state. Everything else R15 verbatim.
// Neutral result => walker is at its structural floor (1 random L2 line
// per walk-step, 32-step serial chain) -> declare roofline next.

#define DEG 16
#define NMAX 131072          // row-count limit of the packed table
#define PACK_BLOCK 256
#define ENT_MASK 0x3FFFFu    // 18-bit entries

// Packed adjacency: 9 dwords/row = 16 x 18-bit entries, +2 dwords pad so
// the last row's entry-15 dwordx2 (dwords 8,9) stays in-bounds.
__device__ unsigned int g_pk32[(size_t)NMAX * 9 + 2];
__device__ int g_flag;   // == epoch  =>  take the general fallback

__global__ __launch_bounds__(PACK_BLOCK) void pack_check_kernel(
    const int* __restrict__ adj_nodes,
    const int* __restrict__ adj_offset,
    const int* __restrict__ degrees,
    int n, int epoch) {
    __shared__ __align__(16) unsigned int lds[PACK_BLOCK * 9];

    int tid = threadIdx.x;
    int blockStart = blockIdx.x * PACK_BLOCK;
    int v = blockStart + tid;

    bool bad = false;
    if (v < n) {
        bad = (degrees[v] != DEG) || (adj_offset[v] != v * DEG);

        const uint4* row4 = (const uint4*)(adj_nodes + (size_t)v * DEG); // 64B-aligned
        uint4 r[4];
        r[0] = row4[0]; r[1] = row4[1]; r[2] = row4[2]; r[3] = row4[3];
        const unsigned* rr = (const unsigned*)r;

        unsigned dw[9];
#pragma unroll
        for (int j = 0; j < 9; ++j) dw[j] = 0u;
#pragma unroll
        for (int e = 0; e < 16; ++e) {
            unsigned id = rr[e];
            if (id >= 262144u) bad = true;            // needs >18 bits
            unsigned s   = 18u * (unsigned)e;
            unsigned d   = s >> 5;
            unsigned off = s & 31u;
            dw[d] |= id << off;
            if (off > 14u) dw[d + 1] |= id >> (32u - off);  // field crosses dword
        }
        // register-level decode check through the walker's exact alignbit
        // path (guards pack logic; ~100 VALU ops, no memory traffic)
#pragma unroll
        for (int e = 0; e < 16; ++e) {
            unsigned s   = 18u * (unsigned)e;
            unsigned d   = s >> 5;
            unsigned off = s & 31u;
            unsigned hi  = (off > 14u) ? dw[d + 1] : 0u;   // crossing d's are <=7
            unsigned id  = __builtin_amdgcn_alignbit(hi, dw[d], off) & ENT_MASK;
            if (id != rr[e]) bad = true;
        }
#pragma unroll
        for (int j = 0; j < 9; ++j) lds[tid * 9 + j] = dw[j];
    }
    __syncthreads();

    // coalesced flush: 256 rows * 9 dwords = 2304 dwords = 576 uint4
    int rows = n - blockStart;
    if (rows > PACK_BLOCK) rows = PACK_BLOCK;
    unsigned int* dstBase = g_pk32 + (size_t)blockStart * 9;   // 16B-aligned (9216B/block)
    if (rows == PACK_BLOCK) {
        uint4* dst4 = (uint4*)dstBase;
        const uint4* src4 = (const uint4*)lds;
        for (int i = tid; i < (PACK_BLOCK * 9) / 4; i += PACK_BLOCK)
            dst4[i] = src4[i];
    } else {
        int ndw = rows * 9;
        for (int i = tid; i < ndw; i += PACK_BLOCK) dstBase[i] = lds[i];
    }

    if (bad) g_flag = epoch;
}

template <int STEPS>
__global__ __launch_bounds__(256) void walker_fast8(
    const int* __restrict__ choices,
    int* __restrict__ out, int n, int epoch,
    const int* __restrict__ adj_nodes,
    const int* __restrict__ adj_offset,
    const int* __restrict__ degrees) {

    int w = blockIdx.x * blockDim.x + threadIdx.x;
    if (w >= n) return;

    int* walks      = out;                    // [STEPS+1, n]
    int* walk_edges = out + (STEPS + 1) * n;  // [STEPS, n]

    __builtin_nontemporal_store(w, &walks[w]);

    if (g_flag != epoch) {
        // ---- fast path: 1 chain/thread, 32-deep choices burst (pays the
        // cold-stream vmcnt drain ONCE — R14's lesson), then the serial
        // chain of single dwordx2 gathers + predicated same-row alt ----
        int c[STEPS];
#pragma unroll
        for (int i = 0; i < STEPS; ++i)
            c[i] = __builtin_nontemporal_load(&choices[i * n + w]);

        int prev = -1, cur = w;
#pragma unroll
        for (int i = 0; i < STEPS; ++i) {
            unsigned ch = (unsigned)c[i];
            unsigned e = ch & (DEG - 1);
            const unsigned* row = g_pk32 + (size_t)(unsigned)cur * 9u;
            unsigned s = 18u * e, d = s >> 5, f = s & 31u;

            uint2 q = *(const uint2*)(row + d);       // one 8B gather (4B-aligned)
            int cand = (int)(__builtin_amdgcn_alignbit(q.y, q.x, f) & ENT_MASK);

            int nw = cand;
            unsigned ef = e;
            // predicated alt: ~4 lanes/wave, same row (hot line)
            if (cand == prev) {
                unsigned a  = (e + 1u + ch % (DEG - 1)) & (DEG - 1);
                unsigned sa = 18u * a, da = sa >> 5, fa = sa & 31u;
                uint2 qa = *(const uint2*)(row + da);
                nw = (int)(__builtin_amdgcn_alignbit(qa.y, qa.x, fa) & ENT_MASK);
                ef = a;
            }

            __builtin_nontemporal_store(nw, &walks[(i + 1) * n + w]);
            __builtin_nontemporal_store((cur << 4) + (int)ef, &walk_edges[i * n + w]);
            prev = cur; cur = nw;
        }
    } else {
        // ---- general fallback: 2 dependent gathers/step from raw CSR ----
        int prev = -1, cur = w;
        for (int i = 0; i < STEPS; ++i) {
            int chv = choices[i * n + w];
            int deg = degrees[cur];
            int off = adj_offset[cur];
            int nb  = deg - 1 > 1 ? deg - 1 : 1;

            int e      = chv % deg;
            int chosen = off + e;
            int alt    = off + (e + 1 + chv % nb) % deg;

            int nv0 = adj_nodes[chosen];
            int nv1 = adj_nodes[alt];

            bool bt = (nv0 == prev);
            int nw  = bt ? nv1 : nv0;
            walks[(i + 1) * n + w] = nw;
            walk_edges[i * n + w]  = bt ? alt : chosen;
            prev = cur;
            cur  = nw;
        }
    }
}

__global__ __launch_bounds__(256) void walker_generic(
    const int* __restrict__ adj_nodes,
    const int* __restrict__ adj_offset,
    const int* __restrict__ degrees,
    const int* __restrict__ choices,
    int* __restrict__ out, int n, int steps) {

    int w = blockIdx.x * blockDim.x + threadIdx.x;
    if (w >= n) return;

    int* walks      = out;
    int* walk_edges = out + (steps + 1) * n;
    walks[w] = w;

    int prev = -1, cur = w;
    for (int i = 0; i < steps; ++i) {
        int chv = choices[i * n + w];
        int deg = degrees[cur];
        int off = adj_offset[cur];
        int nb  = deg - 1 > 1 ? deg - 1 : 1;

        int e      = chv % deg;
        int chosen = off + e;
        int alt    = off + (e + 1 + chv % nb) % deg;

        int nv0 = adj_nodes[chosen];
        int nv1 = adj_nodes[alt];

        bool bt = (nv0 == prev);
        int nw  = bt ? nv1 : nv0;
        walks[(i + 1) * n + w] = nw;
        walk_edges[i * n + w]  = bt ? alt : chosen;
        prev = cur;
        cur  = nw;
    }
}

extern "C" void kernel_launch(void* const* d_in, const int* in_sizes, int n_in,
                              void* d_out, int out_size, void* d_ws, size_t ws_size,
                              hipStream_t stream) {
    // inputs: 0=x (unused), 1=adj_nodes, 2=adj_offset, 3=degrees, 4=choices
    const int* adj_nodes  = (const int*)d_in[1];
    const int* adj_offset = (const int*)d_in[2];
    const int* degrees    = (const int*)d_in[3];
    const int* choices    = (const int*)d_in[4];
    int* out = (int*)d_out;

    int n     = in_sizes[2];
    int steps = in_sizes[4] / n;

    if (steps == 32 && n <= NMAX) {
        static int s_epoch = 0;
        int epoch = ++s_epoch;   // baked into a captured graph; pack reruns
                                 // per replay, badness is input-constant

        int pg = (n + PACK_BLOCK - 1) / PACK_BLOCK;
        pack_check_kernel<<<pg, PACK_BLOCK, 0, stream>>>(adj_nodes, adj_offset,
                                                         degrees, n, epoch);

        int wb = 256, wg = (n + wb - 1) / wb;
        walker_fast8<32><<<wg, wb, 0, stream>>>(choices, out, n, epoch,
                                                adj_nodes, adj_offset, degrees);
    } else {
        int block = 256, grid = (n + block - 1) / block;
        walker_generic<<<grid, block, 0, stream>>>(adj_nodes, adj_offset,
                                                   degrees, choices, out, n, steps);
    }
}